// Round 8
// baseline (172.038 us; speedup 1.0000x reference)
//
#include <hip/hip_runtime.h>
#include <cstdint>

// ChessGNN forward, MI355X.
// R7: back to 3 blocks/CU (LDS padded to 41,216B; launch_bounds(512,6) —
//     the 4/CU + VGPR-32 regime of R5/R6 regressed). LDS-instr diet:
//     h stored f16 (phase-6 reads halved, fma_mix accum), phase-2-L0 via
//     MFMA (K padded to 32), phase-6 (nr,c8) mapping, transpose BN reduce.

#define BB   2048
#define NN   90
#define NP   96
#define CC   64
#define NH   4
#define HD   16
#define TPB  512
#define DOUT 128
#define SXP  72      // sx / sh16 row pitch (f16)
#define SWP  72      // sWt row pitch (f16)
#define XRP  32      // sXr / sInWt row pitch (f16), K padded to 32
#define PPITCH 20    // sPh row pitch (f16)
#define RPITCH 68    // sRa/sRb row pitch (f32)
#define NSLOT 19

typedef _Float16 f16;
typedef _Float16 f16x4 __attribute__((ext_vector_type(4)));
typedef _Float16 f16x8 __attribute__((ext_vector_type(8)));
typedef float f32x4 __attribute__((ext_vector_type(4)));
union U16x8 { f16x8 v; f16 e[8]; };
union U16x4 { f16x4 v; f16 e[4]; };

// LDS map (bytes), declared 41,216 (pads past 40,960 -> 3 blocks/CU):
//  [0,13824)      sx f16[96][72]  ->  sh16 f16[96][72] (phase-3 overlay)
//  [13824,23040)  sWt f16[64][72]           (dead after phase-3 preload)
//  [23040,29184)  sXr f16[96][32]   (L0, dead after phase 2)
//  [29184,33280)  sInWt f16[64][32] (L0, dead after phase 2)
//  [33280,33536)  sInb f32[64] (L0)
//  [33536,33792)  sAs f32[64]   [33792,34048) sAd f32[64]
//  [13824,28224)  sPh f16[360][20]  (phases 5-6; overlays sWt+sXr)
//  [34816,36256)  sSrc f32[360]   [36256,37696) sDst f32[360]
//  [37696,38208)  sST f32[128] (L1)
//  phase 7: sRa f32[64][68] @0 (17408), sRb @17408 (->34816),
//           sP2a f32[512] @34816, sP2b @36864 (overlay sSrc/sDst, dead)
#define LDS_BYTES 41216

template <int LAYER>
__global__ __launch_bounds__(TPB, 6) void k_gat(
    const float* __restrict__ bp,
    const float* __restrict__ inW,
    const float* __restrict__ inb,
    const float* __restrict__ prevPre,
    const float* __restrict__ stPrev,
    const float* __restrict__ Wl,
    const float* __restrict__ asrc,
    const float* __restrict__ adst,
    float* __restrict__ outPre,
    float* __restrict__ partial,
    float* __restrict__ partialSq)
{
    __shared__ __align__(16) unsigned char lds[LDS_BYTES];
    f16*   sx    = (f16*)lds;                    // [96][72] phases 1-3
    f16*   sh16  = (f16*)lds;                    // [96][72] phases 3-6 (overlay)
    f16*   sWt   = (f16*)(lds + 13824);          // [64][72]
    f16*   sXr   = (f16*)(lds + 23040);          // [96][32] L0
    f16*   sInWt = (f16*)(lds + 29184);          // [64][32] L0
    float* sInb  = (float*)(lds + 33280);        // [64] L0
    float* sAs   = (float*)(lds + 33536);        // [64]
    float* sAd   = (float*)(lds + 33792);        // [64]
    f16*   sPh   = (f16*)(lds + 13824);          // [360][20] phases 5-6
    float* sSrc  = (float*)(lds + 34816);        // [360]
    float* sDst  = (float*)(lds + 36256);        // [360]
    float* sST   = (float*)(lds + 37696);        // [128] L1
    float* sRa   = (float*)lds;                  // [64][68] phase 7
    float* sRb   = (float*)(lds + 17408);
    float* sP2a  = (float*)(lds + 34816);        // [512] phase 7
    float* sP2b  = (float*)(lds + 36864);

    const int b = blockIdx.x, t = threadIdx.x;
    const int lane = t & 63, wv = t >> 6;
    const int lr = lane & 15, lg = lane >> 4;

    // ---------------- phase 1: staging
    for (int i = t; i < CC * CC; i += TPB) {
        int k = i >> 6, c = i & 63;
        sWt[c * SWP + k] = (f16)Wl[i];
    }
    if (t < NH * HD) { sAs[t] = asrc[t]; sAd[t] = adst[t]; }
    if (LAYER == 0) {
        // board planes -> sXr (k<14), pos (k=14,15); zero k 16..31
        for (int i = t; i < 14 * NN; i += TPB) {
            int n = i / 14, p = i - n * 14;
            sXr[n * XRP + p] = (f16)bp[(size_t)b * (14 * NN) + p * NN + n];
        }
        if (t < NN) {
            int y = t / 9, x = t - y * 9;
            sXr[t * XRP + 14] = (f16)((float)x / 9.0f);
            sXr[t * XRP + 15] = (f16)((float)y / 10.0f);
        }
        if (t < NP * 2) {   // zero sXr[row][16..31]
            f16x8 z = {};
            *(f16x8*)&sXr[(t >> 1) * XRP + 16 + (t & 1) * 8] = z;
        }
        for (int i = t; i < 16 * CC; i += TPB) {   // sInWt[c][k] = inW[k][c]
            int c = i >> 4, k = i & 15;
            sInWt[c * XRP + k] = (f16)inW[k * CC + c];
        }
        if (t < CC * 2) {   // zero sInWt[c][16..31]
            f16x8 z = {};
            *(f16x8*)&sInWt[(t >> 1) * XRP + 16 + (t & 1) * 8] = z;
        }
        if (t < CC) sInb[t] = inb[t];
    } else {
        if (t < 2 * CC) sST[t] = stPrev[t];
    }
    __syncthreads();

    // ---------------- phase 2: x -> sx (f16)
    if (LAYER == 0) {
        // x = board @ inW + b via MFMA 16x16x32 (K padded to 32 with zeros)
        const int nt = wv & 3, m0 = wv >> 2;
        const f16x8 bf = *(const f16x8*)&sInWt[(nt * 16 + lr) * XRP + lg * 8];
        const float bias = sInb[nt * 16 + lr];
        #pragma unroll
        for (int mi = 0; mi < 3; mi++) {
            const int mt = m0 + 2 * mi;
            const f16x8 af = *(const f16x8*)&sXr[(mt * 16 + lr) * XRP + lg * 8];
            f32x4 acc = {0.0f, 0.0f, 0.0f, 0.0f};
            acc = __builtin_amdgcn_mfma_f32_16x16x32_f16(af, bf, acc, 0, 0, 0);
            const int row = mt * 16 + lg * 4, col = nt * 16 + lr;
            #pragma unroll
            for (int r = 0; r < 4; r++)
                sx[(row + r) * SXP + col] = (f16)(acc[r] + bias);
        }
    } else {
        const float4* pv4 = (const float4*)(prevPre + (size_t)b * (NN * CC));
        for (int i4 = t; i4 < NN * CC / 4; i4 += TPB) {
            float4 v = pv4[i4];
            int n = i4 >> 4, c = (i4 & 15) << 2;
            float a0 = fmaf(v.x, sST[c + 0], sST[CC + c + 0]);
            float a1 = fmaf(v.y, sST[c + 1], sST[CC + c + 1]);
            float a2 = fmaf(v.z, sST[c + 2], sST[CC + c + 2]);
            float a3 = fmaf(v.w, sST[c + 3], sST[CC + c + 3]);
            f16x4 o;
            o.x = (f16)(a0 > 0.0f ? a0 : 0.0f);
            o.y = (f16)(a1 > 0.0f ? a1 : 0.0f);
            o.z = (f16)(a2 > 0.0f ? a2 : 0.0f);
            o.w = (f16)(a3 > 0.0f ? a3 : 0.0f);
            *(f16x4*)&sx[n * SXP + c] = o;
        }
    }
    __syncthreads();

    // ---------------- phase 3: h = x @ W via MFMA; C stored f16 over sx
    {
        const int nt = wv & 3, m0 = wv >> 2;
        const f16x8 bf0 = *(const f16x8*)&sWt[(nt * 16 + lr) * SWP + lg * 8];
        const f16x8 bf1 = *(const f16x8*)&sWt[(nt * 16 + lr) * SWP + 32 + lg * 8];
        f16x8 af0[3], af1[3];
        #pragma unroll
        for (int mi = 0; mi < 3; mi++) {
            const int mt = m0 + 2 * mi;
            af0[mi] = *(const f16x8*)&sx[(mt * 16 + lr) * SXP + lg * 8];
            af1[mi] = *(const f16x8*)&sx[(mt * 16 + lr) * SXP + 32 + lg * 8];
        }
        __syncthreads();   // all sx/sWt reads done; sh16 writes may begin
        #pragma unroll
        for (int mi = 0; mi < 3; mi++) {
            const int mt = m0 + 2 * mi;
            f32x4 acc = {0.0f, 0.0f, 0.0f, 0.0f};
            acc = __builtin_amdgcn_mfma_f32_16x16x32_f16(af0[mi], bf0, acc, 0, 0, 0);
            acc = __builtin_amdgcn_mfma_f32_16x16x32_f16(af1[mi], bf1, acc, 0, 0, 0);
            const int row = mt * 16 + lg * 4, col = nt * 16 + lr;
            #pragma unroll
            for (int r = 0; r < 4; r++)
                sh16[(row + r) * SXP + col] = (f16)acc[r];
        }
    }
    __syncthreads();

    // ---------------- phase 4: attention scores (f16 h, fma_mix) -> f32
    if (t < NH * NN) {
        int hh = t / NN, n = t - hh * NN;
        U16x8 h0, h1;
        h0.v = *(const f16x8*)&sh16[n * SXP + hh * HD];
        h1.v = *(const f16x8*)&sh16[n * SXP + hh * HD + 8];
        float a = 0.0f, d = 0.0f;
        #pragma unroll
        for (int j = 0; j < 8; j++) {
            a = fmaf((float)h0.e[j], sAs[hh * HD + j], a);
            a = fmaf((float)h1.e[j], sAs[hh * HD + 8 + j], a);
            d = fmaf((float)h0.e[j], sAd[hh * HD + j], d);
            d = fmaf((float)h1.e[j], sAd[hh * HD + 8 + j], d);
        }
        sSrc[t] = a; sDst[t] = d;
    }
    __syncthreads();

    // ---------------- phase 5: positional-slot softmax -> sPh (f16, normalized)
    if (t < NH * NN) {
        int hh = t / NN, n = t - hh * NN;
        int y = n / 9, x = n - y * 9;
        float si = sSrc[t];
        float e[NSLOT];
        #pragma unroll
        for (int xx = 0; xx < 9; xx++) {
            int dx = xx > x ? xx - x : x - xx;
            float ee = si + sDst[hh * NN + y * 9 + xx];
            ee = ee > 0.0f ? ee : 0.2f * ee;
            e[xx] = (dx <= 4) ? ee : -1e30f;
        }
        #pragma unroll
        for (int yy = 0; yy < 10; yy++) {
            int dy = yy > y ? yy - y : y - yy;
            float ee = si + sDst[hh * NN + yy * 9 + x];
            ee = ee > 0.0f ? ee : 0.2f * ee;
            e[9 + yy] = (dy >= 1 && dy <= 5) ? ee : -1e30f;
        }
        float m = e[0];
        #pragma unroll
        for (int k = 1; k < NSLOT; k++) m = fmaxf(m, e[k]);
        float p[NSLOT];
        float s = 0.0f;
        #pragma unroll
        for (int k = 0; k < NSLOT; k++) { p[k] = __expf(e[k] - m); s += p[k]; }
        float inv = 1.0f / s;
        f16* pr = &sPh[t * PPITCH];
        #pragma unroll
        for (int q = 0; q < 5; q++) {
            U16x4 o;
            #pragma unroll
            for (int j = 0; j < 4; j++) {
                int k = 4 * q + j;
                o.e[j] = (k < NSLOT) ? (f16)(p[k] * inv) : (f16)0;
            }
            *(f16x4*)&pr[4 * q] = o.v;
        }
    }
    __syncthreads();

    // ---------------- phase 6: out = attn @ h (f16 h, 8 ch/thread, fma_mix)
    const int c8i = t & 7, nr = t >> 3;
    const int ch = c8i << 3, hh6 = c8i >> 1;
    const int nrows = (nr < NN - 64) ? 2 : 1;
    float lsum[8] = {}, lsq[8] = {};
    float* op = outPre + (size_t)b * (NN * CC);
    for (int j = 0; j < nrows; j++) {
        int n = nr + 64 * j;
        int y = n / 9, x = n - y * 9;
        const f16* pr = &sPh[(hh6 * NN + n) * PPITCH];
        U16x4 P0, P1, P2, P3, P4;
        P0.v = *(const f16x4*)&pr[0];
        P1.v = *(const f16x4*)&pr[4];
        P2.v = *(const f16x4*)&pr[8];
        P3.v = *(const f16x4*)&pr[12];
        P4.v = *(const f16x4*)&pr[16];
        float a[8] = {};
        #pragma unroll
        for (int xx = 0; xx < 9; xx++) {
            float p = (xx < 4) ? (float)P0.e[xx]
                    : (xx < 8) ? (float)P1.e[xx - 4] : (float)P2.e[0];
            U16x8 h8; h8.v = *(const f16x8*)&sh16[(y * 9 + xx) * SXP + ch];
            #pragma unroll
            for (int q = 0; q < 8; q++) a[q] = fmaf((float)h8.e[q], p, a[q]);
        }
        #pragma unroll
        for (int yy = 0; yy < 10; yy++) {
            int k = 9 + yy;
            float p = (k < 12) ? (float)P2.e[k - 8]
                    : (k < 16) ? (float)P3.e[k - 12] : (float)P4.e[k - 16];
            U16x8 h8; h8.v = *(const f16x8*)&sh16[(yy * 9 + x) * SXP + ch];
            #pragma unroll
            for (int q = 0; q < 8; q++) a[q] = fmaf((float)h8.e[q], p, a[q]);
        }
        float4 o1, o2;
        o1.x = a[0]; o1.y = a[1]; o1.z = a[2]; o1.w = a[3];
        o2.x = a[4]; o2.y = a[5]; o2.z = a[6]; o2.w = a[7];
        *(float4*)&op[n * CC + ch] = o1;
        *(float4*)&op[n * CC + ch + 4] = o2;
        #pragma unroll
        for (int q = 0; q < 8; q++) {
            lsum[q] += a[q];
            lsq[q] = fmaf(a[q], a[q], lsq[q]);
        }
    }
    __syncthreads();   // sPh/sh16 dead beyond here

    // ---------------- phase 7: BN partials (3-stage LDS transpose reduce)
    {
        float4 w1, w2;
        w1.x = lsum[0]; w1.y = lsum[1]; w1.z = lsum[2]; w1.w = lsum[3];
        w2.x = lsum[4]; w2.y = lsum[5]; w2.z = lsum[6]; w2.w = lsum[7];
        *(float4*)&sRa[nr * RPITCH + ch] = w1;
        *(float4*)&sRa[nr * RPITCH + ch + 4] = w2;
        w1.x = lsq[0]; w1.y = lsq[1]; w1.z = lsq[2]; w1.w = lsq[3];
        w2.x = lsq[4]; w2.y = lsq[5]; w2.z = lsq[6]; w2.w = lsq[7];
        *(float4*)&sRb[nr * RPITCH + ch] = w1;
        *(float4*)&sRb[nr * RPITCH + ch + 4] = w2;
    }
    __syncthreads();
    {
        const int c = t & 63, part = t >> 6;
        float s = 0.0f, q = 0.0f;
        #pragma unroll
        for (int g = 0; g < 8; g++) {
            int row = part + 8 * g;
            s += sRa[row * RPITCH + c];
            q += sRb[row * RPITCH + c];
        }
        sP2a[part * CC + c] = s;
        sP2b[part * CC + c] = q;
    }
    __syncthreads();
    if (t < CC) {
        float s = 0.0f, q = 0.0f;
        #pragma unroll
        for (int p = 0; p < 8; p++) {
            s += sP2a[p * CC + t];
            q += sP2b[p * CC + t];
        }
        partial[(size_t)b * CC + t] = s;
        partialSq[(size_t)b * CC + t] = q;
    }
}

// ------------------------------------------------------------- BN statistics
__global__ __launch_bounds__(256) void k_stats(
    const float* __restrict__ partial, const float* __restrict__ partialSq,
    const float* __restrict__ gamma, const float* __restrict__ beta,
    float* __restrict__ st)
{
    const int c = blockIdx.x, t = threadIdx.x;
    float s = 0.0f, q = 0.0f;
    for (int b = t; b < BB; b += 256) {
        s += partial[(size_t)b * CC + c];
        q += partialSq[(size_t)b * CC + c];
    }
    __shared__ float rs[256], rq[256];
    rs[t] = s; rq[t] = q;
    __syncthreads();
    for (int o = 128; o > 0; o >>= 1) {
        if (t < o) { rs[t] += rs[t + o]; rq[t] += rq[t + o]; }
        __syncthreads();
    }
    if (t == 0) {
        const float cntInv = 1.0f / (float)(BB * NN);
        float mean = rs[0] * cntInv;
        float var  = rq[0] * cntInv - mean * mean;
        float sc = gamma[c] * rsqrtf(var + 1e-5f);
        st[c] = sc;
        st[CC + c] = beta[c] - mean * sc;
    }
}

// ------------------------------------------------------------------- final
__global__ __launch_bounds__(256) void k_final(
    const float* __restrict__ pre, const float* __restrict__ st,
    const float* __restrict__ outW, const float* __restrict__ outb,
    float* __restrict__ out)
{
    __shared__ float sM[CC];
    __shared__ float sPart[4][CC];
    const int b = blockIdx.x, t = threadIdx.x;
    const int c = t & 63, p = t >> 6;
    const float* pv = pre + (size_t)b * (NN * CC);
    float s = st[c], sft = st[CC + c];
    float a = 0.0f;
    int nBeg = p * 23, nEnd = nBeg + 23 < NN ? nBeg + 23 : NN;
    for (int n = nBeg; n < nEnd; n++) {
        float v = fmaf(pv[n * CC + c], s, sft);
        a += (v > 0.0f ? v : 0.0f);
    }
    sPart[p][c] = a;
    __syncthreads();
    if (t < CC)
        sM[t] = (sPart[0][t] + sPart[1][t] + sPart[2][t] + sPart[3][t]) * (1.0f / (float)NN);
    __syncthreads();
    if (t < DOUT) {
        float acc = outb[t];
        #pragma unroll
        for (int cc2 = 0; cc2 < CC; cc2++) acc = fmaf(sM[cc2], outW[cc2 * DOUT + t], acc);
        out[(size_t)b * DOUT + t] = acc;
    }
}

// ------------------------------------------------------------------ launch
extern "C" void kernel_launch(void* const* d_in, const int* in_sizes, int n_in,
                              void* d_out, int out_size, void* d_ws, size_t ws_size,
                              hipStream_t stream) {
    (void)in_sizes; (void)n_in; (void)out_size; (void)ws_size;

    const float* bp   = (const float*)d_in[0];
    const float* inW  = (const float*)d_in[1];
    const float* inb  = (const float*)d_in[2];
    const float* W0   = (const float*)d_in[3];
    const float* as0  = (const float*)d_in[4];
    const float* ad0  = (const float*)d_in[5];
    const float* g0   = (const float*)d_in[6];
    const float* b0   = (const float*)d_in[7];
    const float* W1   = (const float*)d_in[8];
    const float* as1  = (const float*)d_in[9];
    const float* ad1  = (const float*)d_in[10];
    const float* g1   = (const float*)d_in[11];
    const float* b1   = (const float*)d_in[12];
    const float* outW = (const float*)d_in[13];
    const float* outb = (const float*)d_in[14];
    float* out = (float*)d_out;

    float* ws = (float*)d_ws;
    float* outPre    = ws;
    float* partial   = outPre + (size_t)BB * NN * CC;
    float* partialSq = partial + (size_t)BB * CC;
    float* st0       = partialSq + (size_t)BB * CC;
    float* st1       = st0 + 2 * CC;

    k_gat<0><<<BB, TPB, 0, stream>>>(bp, inW, inb, nullptr, nullptr,
                                     W0, as0, ad0, outPre, partial, partialSq);
    k_stats<<<CC, 256, 0, stream>>>(partial, partialSq, g0, b0, st0);
    k_gat<1><<<BB, TPB, 0, stream>>>(nullptr, nullptr, nullptr, outPre, st0,
                                     W1, as1, ad1, outPre, partial, partialSq);
    k_stats<<<CC, 256, 0, stream>>>(partial, partialSq, g1, b1, st1);
    k_final<<<BB, 256, 0, stream>>>(outPre, st1, outW, outb, out);
}

// Round 9
// 111.057 us; speedup vs baseline: 1.5491x; 1.5491x over previous
//
#include <hip/hip_runtime.h>
#include <cstdint>

// ChessGNN forward, MI355X.
// R8 = R4 base (best config) + h stored f16 (same-buffer overlay, phase-6
//     LDS reads halved) + outPre in f16 (HBM halved; BN stats from cast
//     values). Accumulator widths kept small (no spill — R7 lesson).

#define BB   2048
#define NN   90
#define NP   96
#define CC   64
#define NH   4
#define HD   16
#define TPB  512
#define DOUT 128
#define SXP  72      // sx / sh16 row pitch (f16)
#define SWP  72      // sWt row pitch (f16)
#define PPITCH 20    // sPh row pitch (f16)
#define NSLOT 19

typedef _Float16 f16;
typedef _Float16 f16x4 __attribute__((ext_vector_type(4)));
typedef _Float16 f16x8 __attribute__((ext_vector_type(8)));
typedef float f32x4 __attribute__((ext_vector_type(4)));
union U16x4 { f16x4 v; f16 e[4]; };
union U16x8 { f16x8 v; f16 e[8]; };

// LDS (37,440 B total):
//  big[13824]: sx f16[96][72]  ->  sh16 f16[96][72] (phase-3 overlay)
//  uni[19712]: ph1-3: sWt f16[64][72] [0,9216) | sInW f32[16][64] [9216,13312)
//              | sInb f32[64] [13312,13568) | sXr f32[90][17] [13568,19688)
//              ph5-6: sPh f16[360][20] [0,14400)
//              ph7:   sRa f32[2048] [0,8192) | sRb f32[2048] [8192,16384)
//  sAs/sAd f32[64] | sSrc/sDst f32[4][90] | sST f32[128]

template <int LAYER>
__global__ __launch_bounds__(TPB, 6) void k_gat(
    const float* __restrict__ bp,
    const float* __restrict__ inW,
    const float* __restrict__ inb,
    const f16*   __restrict__ prevPre,   // f16 now
    const float* __restrict__ stPrev,
    const float* __restrict__ Wl,
    const float* __restrict__ asrc,
    const float* __restrict__ adst,
    f16*   __restrict__ outPre,          // f16 now
    float* __restrict__ partial,
    float* __restrict__ partialSq)
{
    __shared__ __align__(16) unsigned char big[13824];
    __shared__ __align__(16) unsigned char uni[19712];
    __shared__ float sAs[NH * HD], sAd[NH * HD];
    __shared__ float sSrc[NH][NN], sDst[NH][NN];
    __shared__ float sST[2 * CC];

    f16*   sx   = (f16*)big;                // [96][72] phases 1-3
    f16*   sh16 = (f16*)big;                // [96][72] phases 3-6 (overlay)
    f16*   sWt  = (f16*)uni;
    float* sInW = (float*)(uni + 9216);
    float* sInb = (float*)(uni + 13312);
    float* sXr  = (float*)(uni + 13568);
    f16*   sPh  = (f16*)uni;
    float* sRa  = (float*)uni;
    float* sRb  = (float*)(uni + 8192);

    const int b = blockIdx.x, t = threadIdx.x;
    const int cq = t & 15, ng = t >> 4;
    const int c4 = cq << 2;
    const int jcnt = (ng < NN - 64) ? 3 : 2;
    const int lane = t & 63, wv = t >> 6;
    const int lr = lane & 15, lg = lane >> 4;

    // ---------------- phase 1: stage weights / inputs; zero-pad sx rows 90-95
    for (int i = t; i < CC * CC; i += TPB) {
        int k = i >> 6, c = i & 63;
        sWt[c * SWP + k] = (f16)Wl[i];
    }
    if (t < NH * HD) { sAs[t] = asrc[t]; sAd[t] = adst[t]; }
    if (t < (NP - NN) * (SXP / 4)) {
        int r = t / (SXP / 4), q = t - r * (SXP / 4);
        f16x4 z = {(f16)0, (f16)0, (f16)0, (f16)0};
        *(f16x4*)&sx[(NN + r) * SXP + q * 4] = z;
    }
    if (LAYER == 0) {
        for (int i = t; i < 16 * CC; i += TPB) sInW[i] = inW[i];
        if (t < CC) sInb[t] = inb[t];
        const float* bpb = bp + (size_t)b * (14 * NN);
        for (int i = t; i < 14 * NN; i += TPB) {
            int p = i / NN, n = i - p * NN;
            sXr[n * 17 + p] = bpb[i];
        }
        if (t < NN) {
            int y = t / 9, x = t - y * 9;
            sXr[t * 17 + 14] = (float)x / 9.0f;
            sXr[t * 17 + 15] = (float)y / 10.0f;
        }
    } else {
        if (t < 2 * CC) sST[t] = stPrev[t];
    }
    __syncthreads();

    // ---------------- phase 2: x -> sx (f16)
    if (LAYER == 0) {
        const int n0 = ng, n1 = ng + 32, n2 = (jcnt == 3) ? ng + 64 : ng;
        float acc[3][4] = {};
        #pragma unroll 4
        for (int k = 0; k < 16; k++) {
            float4 w = *(const float4*)&sInW[k * CC + c4];
            float x0 = sXr[n0 * 17 + k], x1 = sXr[n1 * 17 + k], x2 = sXr[n2 * 17 + k];
            acc[0][0] = fmaf(x0, w.x, acc[0][0]); acc[0][1] = fmaf(x0, w.y, acc[0][1]);
            acc[0][2] = fmaf(x0, w.z, acc[0][2]); acc[0][3] = fmaf(x0, w.w, acc[0][3]);
            acc[1][0] = fmaf(x1, w.x, acc[1][0]); acc[1][1] = fmaf(x1, w.y, acc[1][1]);
            acc[1][2] = fmaf(x1, w.z, acc[1][2]); acc[1][3] = fmaf(x1, w.w, acc[1][3]);
            acc[2][0] = fmaf(x2, w.x, acc[2][0]); acc[2][1] = fmaf(x2, w.y, acc[2][1]);
            acc[2][2] = fmaf(x2, w.z, acc[2][2]); acc[2][3] = fmaf(x2, w.w, acc[2][3]);
        }
        float4 bias = *(const float4*)&sInb[c4];
        for (int j = 0; j < jcnt; j++) {
            int n = ng + 32 * j;
            f16x4 o;
            o.x = (f16)(acc[j][0] + bias.x);
            o.y = (f16)(acc[j][1] + bias.y);
            o.z = (f16)(acc[j][2] + bias.z);
            o.w = (f16)(acc[j][3] + bias.w);
            *(f16x4*)&sx[n * SXP + c4] = o;
        }
    } else {
        const f16x8* pv8 = (const f16x8*)(prevPre + (size_t)b * (NN * CC));
        for (int i8 = t; i8 < NN * CC / 8; i8 += TPB) {
            U16x8 v; v.v = pv8[i8];
            int n = i8 >> 3, c8 = (i8 & 7) << 3;
            U16x8 o;
            #pragma unroll
            for (int j = 0; j < 8; j++) {
                float a = fmaf((float)v.e[j], sST[c8 + j], sST[CC + c8 + j]);
                o.e[j] = (f16)(a > 0.0f ? a : 0.0f);
            }
            *(f16x8*)&sx[n * SXP + c8] = o.v;
        }
    }
    __syncthreads();

    // ---------------- phase 3: h = x @ W via MFMA; C cast f16 over sx
    {
        const int nt = wv & 3, m0 = wv >> 2;
        const f16x8 bf0 = *(const f16x8*)&sWt[(nt * 16 + lr) * SWP + lg * 8];
        const f16x8 bf1 = *(const f16x8*)&sWt[(nt * 16 + lr) * SWP + 32 + lg * 8];
        f16x8 af0[3], af1[3];
        #pragma unroll
        for (int mi = 0; mi < 3; mi++) {
            const int mt = m0 + 2 * mi;
            af0[mi] = *(const f16x8*)&sx[(mt * 16 + lr) * SXP + lg * 8];
            af1[mi] = *(const f16x8*)&sx[(mt * 16 + lr) * SXP + 32 + lg * 8];
        }
        __syncthreads();   // all sx/sWt reads done; sh16 writes may begin
        #pragma unroll
        for (int mi = 0; mi < 3; mi++) {
            const int mt = m0 + 2 * mi;
            f32x4 acc = {0.0f, 0.0f, 0.0f, 0.0f};
            acc = __builtin_amdgcn_mfma_f32_16x16x32_f16(af0[mi], bf0, acc, 0, 0, 0);
            acc = __builtin_amdgcn_mfma_f32_16x16x32_f16(af1[mi], bf1, acc, 0, 0, 0);
            const int row = mt * 16 + lg * 4, col = nt * 16 + lr;
            #pragma unroll
            for (int r = 0; r < 4; r++)
                sh16[(row + r) * SXP + col] = (f16)acc[r];
        }
    }
    __syncthreads();

    // ---------------- phase 4: attention scores (f16 h) -> f32 sSrc/sDst
    if (t < NH * NN) {
        int hh = t / NN, n = t - hh * NN;
        U16x8 h0, h1;
        h0.v = *(const f16x8*)&sh16[n * SXP + hh * HD];
        h1.v = *(const f16x8*)&sh16[n * SXP + hh * HD + 8];
        float a = 0.0f, d = 0.0f;
        #pragma unroll
        for (int j = 0; j < 8; j++) {
            a = fmaf((float)h0.e[j], sAs[hh * HD + j], a);
            a = fmaf((float)h1.e[j], sAs[hh * HD + 8 + j], a);
            d = fmaf((float)h0.e[j], sAd[hh * HD + j], d);
            d = fmaf((float)h1.e[j], sAd[hh * HD + 8 + j], d);
        }
        sSrc[hh][n] = a; sDst[hh][n] = d;
    }
    __syncthreads();

    // ---------------- phase 5: positional-slot softmax -> sPh (f16, normalized)
    if (t < NH * NN) {
        int hh = t / NN, n = t - hh * NN;
        int y = n / 9, x = n - y * 9;
        float si = sSrc[hh][n];
        float e[NSLOT];
        #pragma unroll
        for (int xx = 0; xx < 9; xx++) {
            int dx = xx > x ? xx - x : x - xx;
            float ee = si + sDst[hh][y * 9 + xx];
            ee = ee > 0.0f ? ee : 0.2f * ee;
            e[xx] = (dx <= 4) ? ee : -1e30f;
        }
        #pragma unroll
        for (int yy = 0; yy < 10; yy++) {
            int dy = yy > y ? yy - y : y - yy;
            float ee = si + sDst[hh][yy * 9 + x];
            ee = ee > 0.0f ? ee : 0.2f * ee;
            e[9 + yy] = (dy >= 1 && dy <= 5) ? ee : -1e30f;
        }
        float m = e[0];
        #pragma unroll
        for (int k = 1; k < NSLOT; k++) m = fmaxf(m, e[k]);
        float p[NSLOT];
        float s = 0.0f;
        #pragma unroll
        for (int k = 0; k < NSLOT; k++) { p[k] = __expf(e[k] - m); s += p[k]; }
        float inv = 1.0f / s;
        f16* pr = &sPh[t * PPITCH];
        #pragma unroll
        for (int q = 0; q < 5; q++) {
            U16x4 o;
            #pragma unroll
            for (int j = 0; j < 4; j++) {
                int k = 4 * q + j;
                o.e[j] = (k < NSLOT) ? (f16)(p[k] * inv) : (f16)0;
            }
            *(f16x4*)&pr[4 * q] = o.v;
        }
    }
    __syncthreads();

    // ---------------- phase 6: out = attn @ h (f16 h, b64 reads, f16 out)
    const int hh2 = cq >> 2;
    float lsum[4] = {}, lsq[4] = {};
    f16* op = outPre + (size_t)b * (NN * CC);
    for (int j = 0; j < jcnt; j++) {
        int n = ng + 32 * j;
        int y = n / 9, x = n - y * 9;
        const f16* pr = &sPh[(hh2 * NN + n) * PPITCH];
        U16x4 P0, P1, P2, P3, P4;
        P0.v = *(const f16x4*)&pr[0];
        P1.v = *(const f16x4*)&pr[4];
        P2.v = *(const f16x4*)&pr[8];
        P3.v = *(const f16x4*)&pr[12];
        P4.v = *(const f16x4*)&pr[16];
        float a0 = 0.0f, a1 = 0.0f, a2 = 0.0f, a3 = 0.0f;
        #pragma unroll
        for (int xx = 0; xx < 9; xx++) {
            float p = (xx < 4) ? (float)P0.e[xx]
                    : (xx < 8) ? (float)P1.e[xx - 4] : (float)P2.e[0];
            U16x4 h4; h4.v = *(const f16x4*)&sh16[(y * 9 + xx) * SXP + c4];
            a0 = fmaf((float)h4.e[0], p, a0); a1 = fmaf((float)h4.e[1], p, a1);
            a2 = fmaf((float)h4.e[2], p, a2); a3 = fmaf((float)h4.e[3], p, a3);
        }
        #pragma unroll
        for (int yy = 0; yy < 10; yy++) {
            int k = 9 + yy;
            float p = (k < 12) ? (float)P2.e[k - 8]
                    : (k < 16) ? (float)P3.e[k - 12] : (float)P4.e[k - 16];
            U16x4 h4; h4.v = *(const f16x4*)&sh16[(yy * 9 + x) * SXP + c4];
            a0 = fmaf((float)h4.e[0], p, a0); a1 = fmaf((float)h4.e[1], p, a1);
            a2 = fmaf((float)h4.e[2], p, a2); a3 = fmaf((float)h4.e[3], p, a3);
        }
        // cast first, accumulate BN stats from the cast values (consistency)
        U16x4 o;
        o.e[0] = (f16)a0; o.e[1] = (f16)a1; o.e[2] = (f16)a2; o.e[3] = (f16)a3;
        *(f16x4*)&op[n * CC + c4] = o.v;
        float r0 = (float)o.e[0], r1 = (float)o.e[1];
        float r2 = (float)o.e[2], r3 = (float)o.e[3];
        lsum[0] += r0; lsum[1] += r1; lsum[2] += r2; lsum[3] += r3;
        lsq[0] = fmaf(r0, r0, lsq[0]); lsq[1] = fmaf(r1, r1, lsq[1]);
        lsq[2] = fmaf(r2, r2, lsq[2]); lsq[3] = fmaf(r3, r3, lsq[3]);
    }
    __syncthreads();   // sPh dead beyond here

    // ---------------- phase 7: BN partial sums (R4 pattern)
    #pragma unroll
    for (int q = 0; q < 4; q++) {
        sRa[ng * CC + c4 + q] = lsum[q];
        sRb[ng * CC + c4 + q] = lsq[q];
    }
    __syncthreads();
    if (t < CC) {
        float s = 0.0f, q2 = 0.0f;
        #pragma unroll
        for (int g = 0; g < 32; g++) {
            s  += sRa[g * CC + t];
            q2 += sRb[g * CC + t];
        }
        partial[(size_t)b * CC + t] = s;
        partialSq[(size_t)b * CC + t] = q2;
    }
}

// ------------------------------------------------------------- BN statistics
__global__ __launch_bounds__(256) void k_stats(
    const float* __restrict__ partial, const float* __restrict__ partialSq,
    const float* __restrict__ gamma, const float* __restrict__ beta,
    float* __restrict__ st)
{
    const int c = blockIdx.x, t = threadIdx.x;
    float s = 0.0f, q = 0.0f;
    for (int b = t; b < BB; b += 256) {
        s += partial[(size_t)b * CC + c];
        q += partialSq[(size_t)b * CC + c];
    }
    __shared__ float rs[256], rq[256];
    rs[t] = s; rq[t] = q;
    __syncthreads();
    for (int o = 128; o > 0; o >>= 1) {
        if (t < o) { rs[t] += rs[t + o]; rq[t] += rq[t + o]; }
        __syncthreads();
    }
    if (t == 0) {
        const float cntInv = 1.0f / (float)(BB * NN);
        float mean = rs[0] * cntInv;
        float var  = rq[0] * cntInv - mean * mean;
        float sc = gamma[c] * rsqrtf(var + 1e-5f);
        st[c] = sc;
        st[CC + c] = beta[c] - mean * sc;
    }
}

// ------------------------------------------------------------------- final
__global__ __launch_bounds__(256) void k_final(
    const f16* __restrict__ pre, const float* __restrict__ st,
    const float* __restrict__ outW, const float* __restrict__ outb,
    float* __restrict__ out)
{
    __shared__ float sM[CC];
    __shared__ float sPart[4][CC];
    const int b = blockIdx.x, t = threadIdx.x;
    const int c = t & 63, p = t >> 6;
    const f16* pv = pre + (size_t)b * (NN * CC);
    float s = st[c], sft = st[CC + c];
    float a = 0.0f;
    int nBeg = p * 23, nEnd = nBeg + 23 < NN ? nBeg + 23 : NN;
    for (int n = nBeg; n < nEnd; n++) {
        float v = fmaf((float)pv[n * CC + c], s, sft);
        a += (v > 0.0f ? v : 0.0f);
    }
    sPart[p][c] = a;
    __syncthreads();
    if (t < CC)
        sM[t] = (sPart[0][t] + sPart[1][t] + sPart[2][t] + sPart[3][t]) * (1.0f / (float)NN);
    __syncthreads();
    if (t < DOUT) {
        float acc = outb[t];
        #pragma unroll
        for (int cc2 = 0; cc2 < CC; cc2++) acc = fmaf(sM[cc2], outW[cc2 * DOUT + t], acc);
        out[(size_t)b * DOUT + t] = acc;
    }
}

// ------------------------------------------------------------------ launch
extern "C" void kernel_launch(void* const* d_in, const int* in_sizes, int n_in,
                              void* d_out, int out_size, void* d_ws, size_t ws_size,
                              hipStream_t stream) {
    (void)in_sizes; (void)n_in; (void)out_size; (void)ws_size;

    const float* bp   = (const float*)d_in[0];
    const float* inW  = (const float*)d_in[1];
    const float* inb  = (const float*)d_in[2];
    const float* W0   = (const float*)d_in[3];
    const float* as0  = (const float*)d_in[4];
    const float* ad0  = (const float*)d_in[5];
    const float* g0   = (const float*)d_in[6];
    const float* b0   = (const float*)d_in[7];
    const float* W1   = (const float*)d_in[8];
    const float* as1  = (const float*)d_in[9];
    const float* ad1  = (const float*)d_in[10];
    const float* g1   = (const float*)d_in[11];
    const float* b1   = (const float*)d_in[12];
    const float* outW = (const float*)d_in[13];
    const float* outb = (const float*)d_in[14];
    float* out = (float*)d_out;

    unsigned char* ws = (unsigned char*)d_ws;
    // outPre f16: 2048*90*64*2 = 23,592,960 B
    f16*   outPre    = (f16*)ws;
    float* partial   = (float*)(ws + 23592960);            // 524,288 B
    float* partialSq = (float*)(ws + 23592960 + 524288);   // 524,288 B
    float* st0       = (float*)(ws + 23592960 + 1048576);
    float* st1       = st0 + 2 * CC;

    k_gat<0><<<BB, TPB, 0, stream>>>(bp, inW, inb, nullptr, nullptr,
                                     W0, as0, ad0, outPre, partial, partialSq);
    k_stats<<<CC, 256, 0, stream>>>(partial, partialSq, g0, b0, st0);
    k_gat<1><<<BB, TPB, 0, stream>>>(nullptr, nullptr, nullptr, outPre, st0,
                                     W1, as1, ad1, outPre, partial, partialSq);
    k_stats<<<CC, 256, 0, stream>>>(partial, partialSq, g1, b1, st1);
    k_final<<<BB, 256, 0, stream>>>(outPre, st1, outW, outb, out);
}

// Round 10
// 110.886 us; speedup vs baseline: 1.5515x; 1.0015x over previous
//
#include <hip/hip_runtime.h>
#include <cstdint>

// ChessGNN forward, MI355X.
// R8 = R4 base (best config) + h stored f16 (same-buffer overlay, phase-6
//     LDS reads halved) + outPre in f16 (HBM halved; BN stats from cast
//     values). Accumulator widths kept small (no spill — R7 lesson).

#define BB   2048
#define NN   90
#define NP   96
#define CC   64
#define NH   4
#define HD   16
#define TPB  512
#define DOUT 128
#define SXP  72      // sx / sh16 row pitch (f16)
#define SWP  72      // sWt row pitch (f16)
#define PPITCH 20    // sPh row pitch (f16)
#define NSLOT 19

typedef _Float16 f16;
typedef _Float16 f16x4 __attribute__((ext_vector_type(4)));
typedef _Float16 f16x8 __attribute__((ext_vector_type(8)));
typedef float f32x4 __attribute__((ext_vector_type(4)));
union U16x4 { f16x4 v; f16 e[4]; };
union U16x8 { f16x8 v; f16 e[8]; };

// LDS (37,440 B total):
//  big[13824]: sx f16[96][72]  ->  sh16 f16[96][72] (phase-3 overlay)
//  uni[19712]: ph1-3: sWt f16[64][72] [0,9216) | sInW f32[16][64] [9216,13312)
//              | sInb f32[64] [13312,13568) | sXr f32[90][17] [13568,19688)
//              ph5-6: sPh f16[360][20] [0,14400)
//              ph7:   sRa f32[2048] [0,8192) | sRb f32[2048] [8192,16384)
//  sAs/sAd f32[64] | sSrc/sDst f32[4][90] | sST f32[128]

template <int LAYER>
__global__ __launch_bounds__(TPB, 6) void k_gat(
    const float* __restrict__ bp,
    const float* __restrict__ inW,
    const float* __restrict__ inb,
    const f16*   __restrict__ prevPre,   // f16 now
    const float* __restrict__ stPrev,
    const float* __restrict__ Wl,
    const float* __restrict__ asrc,
    const float* __restrict__ adst,
    f16*   __restrict__ outPre,          // f16 now
    float* __restrict__ partial,
    float* __restrict__ partialSq)
{
    __shared__ __align__(16) unsigned char big[13824];
    __shared__ __align__(16) unsigned char uni[19712];
    __shared__ float sAs[NH * HD], sAd[NH * HD];
    __shared__ float sSrc[NH][NN], sDst[NH][NN];
    __shared__ float sST[2 * CC];

    f16*   sx   = (f16*)big;                // [96][72] phases 1-3
    f16*   sh16 = (f16*)big;                // [96][72] phases 3-6 (overlay)
    f16*   sWt  = (f16*)uni;
    float* sInW = (float*)(uni + 9216);
    float* sInb = (float*)(uni + 13312);
    float* sXr  = (float*)(uni + 13568);
    f16*   sPh  = (f16*)uni;
    float* sRa  = (float*)uni;
    float* sRb  = (float*)(uni + 8192);

    const int b = blockIdx.x, t = threadIdx.x;
    const int cq = t & 15, ng = t >> 4;
    const int c4 = cq << 2;
    const int jcnt = (ng < NN - 64) ? 3 : 2;
    const int lane = t & 63, wv = t >> 6;
    const int lr = lane & 15, lg = lane >> 4;

    // ---------------- phase 1: stage weights / inputs; zero-pad sx rows 90-95
    for (int i = t; i < CC * CC; i += TPB) {
        int k = i >> 6, c = i & 63;
        sWt[c * SWP + k] = (f16)Wl[i];
    }
    if (t < NH * HD) { sAs[t] = asrc[t]; sAd[t] = adst[t]; }
    if (t < (NP - NN) * (SXP / 4)) {
        int r = t / (SXP / 4), q = t - r * (SXP / 4);
        f16x4 z = {(f16)0, (f16)0, (f16)0, (f16)0};
        *(f16x4*)&sx[(NN + r) * SXP + q * 4] = z;
    }
    if (LAYER == 0) {
        for (int i = t; i < 16 * CC; i += TPB) sInW[i] = inW[i];
        if (t < CC) sInb[t] = inb[t];
        const float* bpb = bp + (size_t)b * (14 * NN);
        for (int i = t; i < 14 * NN; i += TPB) {
            int p = i / NN, n = i - p * NN;
            sXr[n * 17 + p] = bpb[i];
        }
        if (t < NN) {
            int y = t / 9, x = t - y * 9;
            sXr[t * 17 + 14] = (float)x / 9.0f;
            sXr[t * 17 + 15] = (float)y / 10.0f;
        }
    } else {
        if (t < 2 * CC) sST[t] = stPrev[t];
    }
    __syncthreads();

    // ---------------- phase 2: x -> sx (f16)
    if (LAYER == 0) {
        const int n0 = ng, n1 = ng + 32, n2 = (jcnt == 3) ? ng + 64 : ng;
        float acc[3][4] = {};
        #pragma unroll 4
        for (int k = 0; k < 16; k++) {
            float4 w = *(const float4*)&sInW[k * CC + c4];
            float x0 = sXr[n0 * 17 + k], x1 = sXr[n1 * 17 + k], x2 = sXr[n2 * 17 + k];
            acc[0][0] = fmaf(x0, w.x, acc[0][0]); acc[0][1] = fmaf(x0, w.y, acc[0][1]);
            acc[0][2] = fmaf(x0, w.z, acc[0][2]); acc[0][3] = fmaf(x0, w.w, acc[0][3]);
            acc[1][0] = fmaf(x1, w.x, acc[1][0]); acc[1][1] = fmaf(x1, w.y, acc[1][1]);
            acc[1][2] = fmaf(x1, w.z, acc[1][2]); acc[1][3] = fmaf(x1, w.w, acc[1][3]);
            acc[2][0] = fmaf(x2, w.x, acc[2][0]); acc[2][1] = fmaf(x2, w.y, acc[2][1]);
            acc[2][2] = fmaf(x2, w.z, acc[2][2]); acc[2][3] = fmaf(x2, w.w, acc[2][3]);
        }
        float4 bias = *(const float4*)&sInb[c4];
        for (int j = 0; j < jcnt; j++) {
            int n = ng + 32 * j;
            f16x4 o;
            o.x = (f16)(acc[j][0] + bias.x);
            o.y = (f16)(acc[j][1] + bias.y);
            o.z = (f16)(acc[j][2] + bias.z);
            o.w = (f16)(acc[j][3] + bias.w);
            *(f16x4*)&sx[n * SXP + c4] = o;
        }
    } else {
        const f16x8* pv8 = (const f16x8*)(prevPre + (size_t)b * (NN * CC));
        for (int i8 = t; i8 < NN * CC / 8; i8 += TPB) {
            U16x8 v; v.v = pv8[i8];
            int n = i8 >> 3, c8 = (i8 & 7) << 3;
            U16x8 o;
            #pragma unroll
            for (int j = 0; j < 8; j++) {
                float a = fmaf((float)v.e[j], sST[c8 + j], sST[CC + c8 + j]);
                o.e[j] = (f16)(a > 0.0f ? a : 0.0f);
            }
            *(f16x8*)&sx[n * SXP + c8] = o.v;
        }
    }
    __syncthreads();

    // ---------------- phase 3: h = x @ W via MFMA; C cast f16 over sx
    {
        const int nt = wv & 3, m0 = wv >> 2;
        const f16x8 bf0 = *(const f16x8*)&sWt[(nt * 16 + lr) * SWP + lg * 8];
        const f16x8 bf1 = *(const f16x8*)&sWt[(nt * 16 + lr) * SWP + 32 + lg * 8];
        f16x8 af0[3], af1[3];
        #pragma unroll
        for (int mi = 0; mi < 3; mi++) {
            const int mt = m0 + 2 * mi;
            af0[mi] = *(const f16x8*)&sx[(mt * 16 + lr) * SXP + lg * 8];
            af1[mi] = *(const f16x8*)&sx[(mt * 16 + lr) * SXP + 32 + lg * 8];
        }
        __syncthreads();   // all sx/sWt reads done; sh16 writes may begin
        #pragma unroll
        for (int mi = 0; mi < 3; mi++) {
            const int mt = m0 + 2 * mi;
            f32x4 acc = {0.0f, 0.0f, 0.0f, 0.0f};
            acc = __builtin_amdgcn_mfma_f32_16x16x32_f16(af0[mi], bf0, acc, 0, 0, 0);
            acc = __builtin_amdgcn_mfma_f32_16x16x32_f16(af1[mi], bf1, acc, 0, 0, 0);
            const int row = mt * 16 + lg * 4, col = nt * 16 + lr;
            #pragma unroll
            for (int r = 0; r < 4; r++)
                sh16[(row + r) * SXP + col] = (f16)acc[r];
        }
    }
    __syncthreads();

    // ---------------- phase 4: attention scores (f16 h) -> f32 sSrc/sDst
    if (t < NH * NN) {
        int hh = t / NN, n = t - hh * NN;
        U16x8 h0, h1;
        h0.v = *(const f16x8*)&sh16[n * SXP + hh * HD];
        h1.v = *(const f16x8*)&sh16[n * SXP + hh * HD + 8];
        float a = 0.0f, d = 0.0f;
        #pragma unroll
        for (int j = 0; j < 8; j++) {
            a = fmaf((float)h0.e[j], sAs[hh * HD + j], a);
            a = fmaf((float)h1.e[j], sAs[hh * HD + 8 + j], a);
            d = fmaf((float)h0.e[j], sAd[hh * HD + j], d);
            d = fmaf((float)h1.e[j], sAd[hh * HD + 8 + j], d);
        }
        sSrc[hh][n] = a; sDst[hh][n] = d;
    }
    __syncthreads();

    // ---------------- phase 5: positional-slot softmax -> sPh (f16, normalized)
    if (t < NH * NN) {
        int hh = t / NN, n = t - hh * NN;
        int y = n / 9, x = n - y * 9;
        float si = sSrc[hh][n];
        float e[NSLOT];
        #pragma unroll
        for (int xx = 0; xx < 9; xx++) {
            int dx = xx > x ? xx - x : x - xx;
            float ee = si + sDst[hh][y * 9 + xx];
            ee = ee > 0.0f ? ee : 0.2f * ee;
            e[xx] = (dx <= 4) ? ee : -1e30f;
        }
        #pragma unroll
        for (int yy = 0; yy < 10; yy++) {
            int dy = yy > y ? yy - y : y - yy;
            float ee = si + sDst[hh][yy * 9 + x];
            ee = ee > 0.0f ? ee : 0.2f * ee;
            e[9 + yy] = (dy >= 1 && dy <= 5) ? ee : -1e30f;
        }
        float m = e[0];
        #pragma unroll
        for (int k = 1; k < NSLOT; k++) m = fmaxf(m, e[k]);
        float p[NSLOT];
        float s = 0.0f;
        #pragma unroll
        for (int k = 0; k < NSLOT; k++) { p[k] = __expf(e[k] - m); s += p[k]; }
        float inv = 1.0f / s;
        f16* pr = &sPh[t * PPITCH];
        #pragma unroll
        for (int q = 0; q < 5; q++) {
            U16x4 o;
            #pragma unroll
            for (int j = 0; j < 4; j++) {
                int k = 4 * q + j;
                o.e[j] = (k < NSLOT) ? (f16)(p[k] * inv) : (f16)0;
            }
            *(f16x4*)&pr[4 * q] = o.v;
        }
    }
    __syncthreads();

    // ---------------- phase 6: out = attn @ h (f16 h, b64 reads, f16 out)
    const int hh2 = cq >> 2;
    float lsum[4] = {}, lsq[4] = {};
    f16* op = outPre + (size_t)b * (NN * CC);
    for (int j = 0; j < jcnt; j++) {
        int n = ng + 32 * j;
        int y = n / 9, x = n - y * 9;
        const f16* pr = &sPh[(hh2 * NN + n) * PPITCH];
        U16x4 P0, P1, P2, P3, P4;
        P0.v = *(const f16x4*)&pr[0];
        P1.v = *(const f16x4*)&pr[4];
        P2.v = *(const f16x4*)&pr[8];
        P3.v = *(const f16x4*)&pr[12];
        P4.v = *(const f16x4*)&pr[16];
        float a0 = 0.0f, a1 = 0.0f, a2 = 0.0f, a3 = 0.0f;
        #pragma unroll
        for (int xx = 0; xx < 9; xx++) {
            float p = (xx < 4) ? (float)P0.e[xx]
                    : (xx < 8) ? (float)P1.e[xx - 4] : (float)P2.e[0];
            U16x4 h4; h4.v = *(const f16x4*)&sh16[(y * 9 + xx) * SXP + c4];
            a0 = fmaf((float)h4.e[0], p, a0); a1 = fmaf((float)h4.e[1], p, a1);
            a2 = fmaf((float)h4.e[2], p, a2); a3 = fmaf((float)h4.e[3], p, a3);
        }
        #pragma unroll
        for (int yy = 0; yy < 10; yy++) {
            int k = 9 + yy;
            float p = (k < 12) ? (float)P2.e[k - 8]
                    : (k < 16) ? (float)P3.e[k - 12] : (float)P4.e[k - 16];
            U16x4 h4; h4.v = *(const f16x4*)&sh16[(yy * 9 + x) * SXP + c4];
            a0 = fmaf((float)h4.e[0], p, a0); a1 = fmaf((float)h4.e[1], p, a1);
            a2 = fmaf((float)h4.e[2], p, a2); a3 = fmaf((float)h4.e[3], p, a3);
        }
        // cast first, accumulate BN stats from the cast values (consistency)
        U16x4 o;
        o.e[0] = (f16)a0; o.e[1] = (f16)a1; o.e[2] = (f16)a2; o.e[3] = (f16)a3;
        *(f16x4*)&op[n * CC + c4] = o.v;
        float r0 = (float)o.e[0], r1 = (float)o.e[1];
        float r2 = (float)o.e[2], r3 = (float)o.e[3];
        lsum[0] += r0; lsum[1] += r1; lsum[2] += r2; lsum[3] += r3;
        lsq[0] = fmaf(r0, r0, lsq[0]); lsq[1] = fmaf(r1, r1, lsq[1]);
        lsq[2] = fmaf(r2, r2, lsq[2]); lsq[3] = fmaf(r3, r3, lsq[3]);
    }
    __syncthreads();   // sPh dead beyond here

    // ---------------- phase 7: BN partial sums (R4 pattern)
    #pragma unroll
    for (int q = 0; q < 4; q++) {
        sRa[ng * CC + c4 + q] = lsum[q];
        sRb[ng * CC + c4 + q] = lsq[q];
    }
    __syncthreads();
    if (t < CC) {
        float s = 0.0f, q2 = 0.0f;
        #pragma unroll
        for (int g = 0; g < 32; g++) {
            s  += sRa[g * CC + t];
            q2 += sRb[g * CC + t];
        }
        partial[(size_t)b * CC + t] = s;
        partialSq[(size_t)b * CC + t] = q2;
    }
}

// ------------------------------------------------------------- BN statistics
__global__ __launch_bounds__(256) void k_stats(
    const float* __restrict__ partial, const float* __restrict__ partialSq,
    const float* __restrict__ gamma, const float* __restrict__ beta,
    float* __restrict__ st)
{
    const int c = blockIdx.x, t = threadIdx.x;
    float s = 0.0f, q = 0.0f;
    for (int b = t; b < BB; b += 256) {
        s += partial[(size_t)b * CC + c];
        q += partialSq[(size_t)b * CC + c];
    }
    __shared__ float rs[256], rq[256];
    rs[t] = s; rq[t] = q;
    __syncthreads();
    for (int o = 128; o > 0; o >>= 1) {
        if (t < o) { rs[t] += rs[t + o]; rq[t] += rq[t + o]; }
        __syncthreads();
    }
    if (t == 0) {
        const float cntInv = 1.0f / (float)(BB * NN);
        float mean = rs[0] * cntInv;
        float var  = rq[0] * cntInv - mean * mean;
        float sc = gamma[c] * rsqrtf(var + 1e-5f);
        st[c] = sc;
        st[CC + c] = beta[c] - mean * sc;
    }
}

// ------------------------------------------------------------------- final
__global__ __launch_bounds__(256) void k_final(
    const f16* __restrict__ pre, const float* __restrict__ st,
    const float* __restrict__ outW, const float* __restrict__ outb,
    float* __restrict__ out)
{
    __shared__ float sM[CC];
    __shared__ float sPart[4][CC];
    const int b = blockIdx.x, t = threadIdx.x;
    const int c = t & 63, p = t >> 6;
    const f16* pv = pre + (size_t)b * (NN * CC);
    float s = st[c], sft = st[CC + c];
    float a = 0.0f;
    int nBeg = p * 23, nEnd = nBeg + 23 < NN ? nBeg + 23 : NN;
    for (int n = nBeg; n < nEnd; n++) {
        float v = fmaf((float)pv[n * CC + c], s, sft);
        a += (v > 0.0f ? v : 0.0f);
    }
    sPart[p][c] = a;
    __syncthreads();
    if (t < CC)
        sM[t] = (sPart[0][t] + sPart[1][t] + sPart[2][t] + sPart[3][t]) * (1.0f / (float)NN);
    __syncthreads();
    if (t < DOUT) {
        float acc = outb[t];
        #pragma unroll
        for (int cc2 = 0; cc2 < CC; cc2++) acc = fmaf(sM[cc2], outW[cc2 * DOUT + t], acc);
        out[(size_t)b * DOUT + t] = acc;
    }
}

// ------------------------------------------------------------------ launch
extern "C" void kernel_launch(void* const* d_in, const int* in_sizes, int n_in,
                              void* d_out, int out_size, void* d_ws, size_t ws_size,
                              hipStream_t stream) {
    (void)in_sizes; (void)n_in; (void)out_size; (void)ws_size;

    const float* bp   = (const float*)d_in[0];
    const float* inW  = (const float*)d_in[1];
    const float* inb  = (const float*)d_in[2];
    const float* W0   = (const float*)d_in[3];
    const float* as0  = (const float*)d_in[4];
    const float* ad0  = (const float*)d_in[5];
    const float* g0   = (const float*)d_in[6];
    const float* b0   = (const float*)d_in[7];
    const float* W1   = (const float*)d_in[8];
    const float* as1  = (const float*)d_in[9];
    const float* ad1  = (const float*)d_in[10];
    const float* g1   = (const float*)d_in[11];
    const float* b1   = (const float*)d_in[12];
    const float* outW = (const float*)d_in[13];
    const float* outb = (const float*)d_in[14];
    float* out = (float*)d_out;

    unsigned char* ws = (unsigned char*)d_ws;
    // outPre f16: 2048*90*64*2 = 23,592,960 B
    f16*   outPre    = (f16*)ws;
    float* partial   = (float*)(ws + 23592960);            // 524,288 B
    float* partialSq = (float*)(ws + 23592960 + 524288);   // 524,288 B
    float* st0       = (float*)(ws + 23592960 + 1048576);
    float* st1       = st0 + 2 * CC;

    k_gat<0><<<BB, TPB, 0, stream>>>(bp, inW, inb, nullptr, nullptr,
                                     W0, as0, ad0, outPre, partial, partialSq);
    k_stats<<<CC, 256, 0, stream>>>(partial, partialSq, g0, b0, st0);
    k_gat<1><<<BB, TPB, 0, stream>>>(nullptr, nullptr, nullptr, outPre, st0,
                                     W1, as1, ad1, outPre, partial, partialSq);
    k_stats<<<CC, 256, 0, stream>>>(partial, partialSq, g1, b1, st1);
    k_final<<<BB, 256, 0, stream>>>(outPre, st1, outW, outb, out);
}